// Round 20
// baseline (295.390 us; speedup 1.0000x reference)
//
#include <hip/hip_runtime.h>
#include <hip/hip_fp16.h>
#include <math.h>

#define N_NODES 50000
#define N_EDGES 1000000
#define F_IN    165
#define KP1     176                         // F_IN padded to 16
#define HID     128
#define HEADS   4
#define F_OUT   32
#define NEG_SLOPE 0.2f
#define NB_SCAN  ((N_NODES + 255) / 256)   // 196 scan blocks
#define NPART    8                          // dst partitions (= XCDs)
#define PART_SZ  (N_NODES / NPART)          // 6250, exact
#define SCHUNKS  256                        // edge chunks for scatter
#define CVT_BLOCKS ((N_NODES * KP1 + 255) / 256)   // 34375
#define PW1_BLOCKS ((11 * 8 * 64 + 255) / 256)     // 22
#define PW2_BLOCKS ((8 * 8 * 64 + 255) / 256)      // 16
#define SCAT_BLOCKS (SCHUNKS * NPART)              // 2048
#define GEMM_BLOCKS ((N_NODES + 63) / 64)          // 782

typedef _Float16 half4v __attribute__((ext_vector_type(4)));
typedef float    f32x4  __attribute__((ext_vector_type(4)));

// ===== device bodies ==========================================================

__device__ __forceinline__ void cvt_body(int bid, const float* __restrict__ X,
                                         __half* __restrict__ Xh) {
    const long long i = (long long)bid * 256 + threadIdx.x;
    if (i >= (long long)N_NODES * KP1) return;
    const int n = (int)(i / KP1);
    const int k = (int)(i - (long long)n * KP1);
    Xh[i] = (k < F_IN) ? __float2half_rn(X[(long long)n * F_IN + k])
                       : __float2half_rn(0.f);
}

__device__ __forceinline__ void pack_body(int bid, const float* __restrict__ W,
                                          __half* __restrict__ Wp,
                                          int K, int ksteps) {
    const int idx = bid * 256 + threadIdx.x;   // (kt*8+ct)*64 + lane
    if (idx >= ksteps * 8 * 64) return;
    const int lane = idx & 63;
    const int tile = idx >> 6;
    const int ct = tile & 7;
    const int kt = tile >> 3;
    const int col = ct * 16 + (lane & 15);
    const int k0 = kt * 16 + 4 * (lane >> 4);
#pragma unroll
    for (int i = 0; i < 4; ++i) {
        const int k = k0 + i;
        Wp[(size_t)idx * 4 + i] = (k < K) ? __float2half_rn(W[(size_t)k * HID + col])
                                          : __float2half_rn(0.f);
    }
}

// GEMM: feat written in QUARTER-PLANE layout featq[q][node][32] so that a
// quarter-slice gather is 64B contiguous and 128B lines never straddle
// quarters (R14's failure mode). el/er epilogue unchanged.
template <int KSTEPS, int KP>
__device__ __forceinline__ void gemm_body(int bid, const __half* __restrict__ Xh,
                                          const __half* __restrict__ Wp,
                                          const float* __restrict__ al,
                                          const float* __restrict__ ar,
                                          __half* __restrict__ feat,
                                          float* __restrict__ el,
                                          float* __restrict__ er) {
    const int tid  = threadIdx.x;
    const int wav  = tid >> 6;
    const int lane = tid & 63;
    const int base = bid * 64 + wav * 16;            // 16-row slice per wave
    if (base >= N_NODES) return;
    const int lr = lane & 15;                         // row (A) / col (B,D)
    const int lq = lane >> 4;                         // k-quad / row-quad

    f32x4 acc[8];
#pragma unroll
    for (int ct = 0; ct < 8; ++ct) acc[ct] = (f32x4){0.f, 0.f, 0.f, 0.f};

    const __half* arow = Xh + (size_t)(base + lr) * KP + 4 * lq;
    for (int kt = 0; kt < KSTEPS; ++kt) {
        const half4v a = *reinterpret_cast<const half4v*>(arow + kt * 16);
        const __half* bp = Wp + ((size_t)kt * 8 * 64 + lane) * 4;
#pragma unroll
        for (int ct = 0; ct < 8; ++ct) {
            const half4v b = *reinterpret_cast<const half4v*>(bp + (size_t)ct * 256);
            acc[ct] = __builtin_amdgcn_mfma_f32_16x16x16f16(a, b, acc[ct], 0, 0, 0);
        }
    }

    float alv[8], arv[8];
#pragma unroll
    for (int ct = 0; ct < 8; ++ct) {
        const int h = ct >> 1;
        const int f = (ct & 1) * 16 + lr;
        alv[ct] = al[h * F_OUT + f];
        arv[ct] = ar[h * F_OUT + f];
    }

#pragma unroll
    for (int i = 0; i < 4; ++i) {
        const int node = base + 4 * lq + i;           // D row = 4*lq + i
        // quarter-plane write: q = ct>>1; offset (ct&1)*16 + lr within quarter
#pragma unroll
        for (int ct = 0; ct < 8; ++ct)
            feat[((size_t)(ct >> 1) * N_NODES + node) * 32 + (ct & 1) * 16 + lr] =
                __float2half_rn(acc[ct][i]);
#pragma unroll
        for (int h = 0; h < 4; ++h) {
            float pl = acc[2 * h][i] * alv[2 * h] + acc[2 * h + 1][i] * alv[2 * h + 1];
            float pr = acc[2 * h][i] * arv[2 * h] + acc[2 * h + 1][i] * arv[2 * h + 1];
            pl += __shfl_xor(pl, 1); pr += __shfl_xor(pr, 1);
            pl += __shfl_xor(pl, 2); pr += __shfl_xor(pr, 2);
            pl += __shfl_xor(pl, 4); pr += __shfl_xor(pr, 4);
            pl += __shfl_xor(pl, 8); pr += __shfl_xor(pr, 8);
            if (lr == 0) {
                el[node * HEADS + h] = pl;
                er[node * HEADS + h] = pr;
            }
        }
    }
}

// rank-based scatter (verbatim R19): no atomics.
__device__ __forceinline__ void scatter_body(int bid, const int* __restrict__ src,
                                             const int* __restrict__ dst,
                                             const int* __restrict__ rowptr,
                                             const int* __restrict__ rank,
                                             int* __restrict__ csr_src) {
    const int part  = bid & (NPART - 1);
    const int chunk = bid >> 3;
    constexpr int CE = (N_EDGES + SCHUNKS - 1) / SCHUNKS;   // 3907
    const int e0 = chunk * CE;
    const int e1 = min(e0 + CE, N_EDGES);
    for (int e = e0 + threadIdx.x; e < e1; e += 256) {
        const int d = dst[e];
        if (d / PART_SZ == part)
            csr_src[rowptr[d] + rank[e]] = src[e];
    }
}

// ===== launch-graph compaction ================================================

__global__ __launch_bounds__(256) void fused_prep(const float* __restrict__ X,
                                                  __half* __restrict__ Xh,
                                                  const float* __restrict__ W1,
                                                  __half* __restrict__ Wp1,
                                                  const float* __restrict__ W2,
                                                  __half* __restrict__ Wp2,
                                                  int* __restrict__ counts) {
    int bid = blockIdx.x;
    if (bid < CVT_BLOCKS) { cvt_body(bid, X, Xh); return; }
    bid -= CVT_BLOCKS;
    if (bid < PW1_BLOCKS) { pack_body(bid, W1, Wp1, F_IN, 11); return; }
    bid -= PW1_BLOCKS;
    if (bid < PW2_BLOCKS) { pack_body(bid, W2, Wp2, HID, 8); return; }
    bid -= PW2_BLOCKS;
    const int i = bid * 256 + threadIdx.x;
    if (i < N_NODES) counts[i] = 0;
}

__global__ __launch_bounds__(256) void hist_dst_rank(const int* __restrict__ dst,
                                                     int* __restrict__ counts,
                                                     int* __restrict__ rank) {
    const int e = blockIdx.x * 256 + threadIdx.x;
    if (e < N_EDGES) rank[e] = atomicAdd(&counts[dst[e]], 1);
}

__global__ __launch_bounds__(256) void fused_scatter_gemm1(
        const int* __restrict__ src, const int* __restrict__ dst,
        const int* __restrict__ rowptr, const int* __restrict__ rank,
        int* __restrict__ csr_src,
        const __half* __restrict__ Xh, const __half* __restrict__ Wp1,
        const float* __restrict__ al1, const float* __restrict__ ar1,
        __half* __restrict__ feat, float* __restrict__ el,
        float* __restrict__ er) {
    if (blockIdx.x < SCAT_BLOCKS)
        scatter_body(blockIdx.x, src, dst, rowptr, rank, csr_src);
    else
        gemm_body<11, KP1>(blockIdx.x - SCAT_BLOCKS, Xh, Wp1, al1, ar1,
                           feat, el, er);
}

__global__ __launch_bounds__(256) void gemm_mfma2(const __half* __restrict__ Xh,
                                                  const __half* __restrict__ Wp,
                                                  const float* __restrict__ al,
                                                  const float* __restrict__ ar,
                                                  __half* __restrict__ feat,
                                                  float* __restrict__ el,
                                                  float* __restrict__ er) {
    gemm_body<8, HID>(blockIdx.x, Xh, Wp, al, ar, feat, el, er);
}

// ================= scan chain =================================================

__global__ __launch_bounds__(256) void scan_local(const int* __restrict__ counts,
                                                  int* __restrict__ rowptr,
                                                  int* __restrict__ blockSums) {
    __shared__ int tmp[256];
    const int i = blockIdx.x * 256 + threadIdx.x;
    const int v = (i < N_NODES) ? counts[i] : 0;
    tmp[threadIdx.x] = v;
    __syncthreads();
#pragma unroll
    for (int off = 1; off < 256; off <<= 1) {
        int t = (threadIdx.x >= off) ? tmp[threadIdx.x - off] : 0;
        __syncthreads();
        tmp[threadIdx.x] += t;
        __syncthreads();
    }
    if (i < N_NODES) rowptr[i] = tmp[threadIdx.x] - v;
    if (threadIdx.x == 255) blockSums[blockIdx.x] = tmp[255];
}

__global__ __launch_bounds__(256) void scan_sums(int* __restrict__ blockSums) {
    __shared__ int tmp[256];
    const int v = (threadIdx.x < NB_SCAN) ? blockSums[threadIdx.x] : 0;
    tmp[threadIdx.x] = v;
    __syncthreads();
#pragma unroll
    for (int off = 1; off < 256; off <<= 1) {
        int t = (threadIdx.x >= off) ? tmp[threadIdx.x - off] : 0;
        __syncthreads();
        tmp[threadIdx.x] += t;
        __syncthreads();
    }
    if (threadIdx.x < NB_SCAN) blockSums[threadIdx.x] = tmp[threadIdx.x] - v;
}

__global__ __launch_bounds__(256) void add_offsets(int* __restrict__ rowptr,
                                                   const int* __restrict__ blockSums) {
    const int i = blockIdx.x * 256 + threadIdx.x;
    if (i < N_NODES)
        rowptr[i] = rowptr[i] + blockSums[blockIdx.x];
    if (i == 0) rowptr[N_NODES] = N_EDGES;
}

// ===== GAT aggregation: QUARTER-plane XCD affinity, 4-way edge groups ========
// Grid: bid -> q = bid&3, nodes (bid>>2)*4 + wave. Round-robin bid->XCD gives
// each XCD ONE 3.2MB plane (L2-resident; the half-split's 6.4MB was not).
// All 32 features of quarter q belong to head q -> one el gather per edge,
// wave-uniform head. Lane = 16*eg + c: FOUR 16-lane edge groups in flight,
// each gather = 16 lanes x half2 = 64B contiguous (one plane line-pair half;
// lines pair adjacent NODES of the same plane -> never cross XCD planes).
// Combine via shfl_xor(16,32). Output hbuf row-major for gemm2/heads.
__global__ __launch_bounds__(256) void gat_aggregate_quarter(
        const int* __restrict__ rowptr, const int* __restrict__ csr_src,
        const float* __restrict__ el, const float* __restrict__ er,
        const __half* __restrict__ feat, __half* __restrict__ outh) {
    const int bid = blockIdx.x;
    const int q   = bid & 3;
    const int d   = (bid >> 2) * 4 + (threadIdx.x >> 6);
    if (d >= N_NODES) return;
    const int lane = threadIdx.x & 63;
    const int eg   = lane >> 4;               // edge group 0..3
    const int c    = lane & 15;               // half2 index within quarter
    const int start = rowptr[d], end = rowptr[d + 1];
    const float erd = er[d * HEADS + q];
    const __half2* __restrict__ fq =
        (const __half2*)feat + (size_t)q * N_NODES * 16;   // plane, 16 half2/row

    float denom = 0.f, ax = 0.f, ay = 0.f;
    for (int chunk = start; chunk < end; chunk += 64) {
        const int cnt = min(64, end - chunk);
        const int idx = chunk + lane;
        const int sv = csr_src[idx < end ? idx : start];
        int t = 0;
        for (; t + 16 <= cnt; t += 16) {  // group eg: edges t+eg, +4, +8, +12
            const unsigned s0 = (unsigned)__shfl(sv, t + eg);
            const unsigned s1 = (unsigned)__shfl(sv, t + 4 + eg);
            const unsigned s2 = (unsigned)__shfl(sv, t + 8 + eg);
            const unsigned s3 = (unsigned)__shfl(sv, t + 12 + eg);
            const float e0 = el[s0 * 4u + q];
            const float e1 = el[s1 * 4u + q];
            const float e2 = el[s2 * 4u + q];
            const float e3 = el[s3 * 4u + q];
            const __half2 q0 = fq[s0 * 16u + c];
            const __half2 q1 = fq[s1 * 16u + c];
            const __half2 q2 = fq[s2 * 16u + c];
            const __half2 q3 = fq[s3 * 16u + c];
            float v0 = e0 + erd; v0 = fmaxf(v0, NEG_SLOPE * v0);
            float v1 = e1 + erd; v1 = fmaxf(v1, NEG_SLOPE * v1);
            float v2 = e2 + erd; v2 = fmaxf(v2, NEG_SLOPE * v2);
            float v3 = e3 + erd; v3 = fmaxf(v3, NEG_SLOPE * v3);
            const float x0 = __expf(v0);
            const float x1 = __expf(v1);
            const float x2 = __expf(v2);
            const float x3 = __expf(v3);
            const float2 f0 = __half22float2(q0);
            const float2 f1 = __half22float2(q1);
            const float2 f2 = __half22float2(q2);
            const float2 f3 = __half22float2(q3);
            denom += (x0 + x1) + (x2 + x3);
            ax += f0.x * x0 + f1.x * x1 + f2.x * x2 + f3.x * x3;
            ay += f0.y * x0 + f1.y * x1 + f2.y * x2 + f3.y * x3;
        }
        for (; t < cnt; t += 4) {         // masked tail
            const int e = t + eg;
            const int ei = e < cnt ? e : 0;
            const unsigned s0 = (unsigned)__shfl(sv, ei);
            const float e0 = el[s0 * 4u + q];
            const __half2 q0 = fq[s0 * 16u + c];
            float v0 = e0 + erd; v0 = fmaxf(v0, NEG_SLOPE * v0);
            float x0 = __expf(v0);
            if (e >= cnt) x0 = 0.f;
            const float2 f0 = __half22float2(q0);
            denom += x0;
            ax += f0.x * x0;
            ay += f0.y * x0;
        }
    }

    // combine the four edge groups (no LDS, no barrier)
    ax    += __shfl_xor(ax, 16);    ax    += __shfl_xor(ax, 32);
    ay    += __shfl_xor(ay, 16);    ay    += __shfl_xor(ay, 32);
    denom += __shfl_xor(denom, 16); denom += __shfl_xor(denom, 32);

    const float inv = 1.f / fmaxf(denom, 1e-9f);
    if (eg == 0)
        ((__half2*)outh)[(size_t)d * 64 + q * 16 + c] =
            __floats2half2_rn(fmaxf(ax * inv, 0.f), fmaxf(ay * inv, 0.f));
}

// ===== MLP heads: thread per (node, MLP) — zero shuffles (verbatim R17) ======
__global__ __launch_bounds__(256) void heads_kernel(const __half* __restrict__ hbuf,
                                                    const float* __restrict__ Wc1,
                                                    const float* __restrict__ bc1,
                                                    const float* __restrict__ Wc2,
                                                    const float* __restrict__ bc2,
                                                    const float* __restrict__ Wf1,
                                                    const float* __restrict__ bf1,
                                                    const float* __restrict__ Wf2,
                                                    const float* __restrict__ bf2,
                                                    float* __restrict__ out) {
    const int which = blockIdx.x & 1;                  // 0=class, 1=confidence
    const int n = (blockIdx.x >> 1) * 256 + threadIdx.x;
    if (n >= N_NODES) return;
    const float* __restrict__ W1 = which ? Wf1 : Wc1;
    const float* __restrict__ b1 = which ? bf1 : bc1;
    const float* __restrict__ W2 = which ? Wf2 : Wc2;
    const float* __restrict__ b2 = which ? bf2 : bc2;
    const __half2* __restrict__ hrow = (const __half2*)hbuf + (size_t)n * 64;

    float a[10];
#pragma unroll
    for (int o = 0; o < 10; ++o) a[o] = b1[o];
    for (int j = 0; j < 64; ++j) {
        const float2 x = __half22float2(hrow[j]);
#pragma unroll
        for (int o = 0; o < 10; ++o)
            a[o] += x.x * W1[(2 * j) * 10 + o] + x.y * W1[(2 * j + 1) * 10 + o];
    }
    float p = b2[0];
#pragma unroll
    for (int o = 0; o < 10; ++o) p += fmaxf(a[o], 0.f) * W2[o];
    out[which * N_NODES + n] = which ? 1.0f / (1.0f + __expf(-p)) : p;
}

extern "C" void kernel_launch(void* const* d_in, const int* in_sizes, int n_in,
                              void* d_out, int out_size, void* d_ws, size_t ws_size,
                              hipStream_t stream) {
    const float* features = (const float*)d_in[0];
    const int*   src      = (const int*)d_in[1];
    const int*   dst      = (const int*)d_in[2];
    const float* W1  = (const float*)d_in[3];
    const float* al1 = (const float*)d_in[4];
    const float* ar1 = (const float*)d_in[5];
    const float* W2  = (const float*)d_in[6];
    const float* al2 = (const float*)d_in[7];
    const float* ar2 = (const float*)d_in[8];
    const float* Wc1 = (const float*)d_in[9];
    const float* bc1 = (const float*)d_in[10];
    const float* Wc2 = (const float*)d_in[11];
    const float* bc2 = (const float*)d_in[12];
    const float* Wf1 = (const float*)d_in[13];
    const float* bf1 = (const float*)d_in[14];
    const float* Wf2 = (const float*)d_in[15];
    const float* bf2 = (const float*)d_in[16];
    float* out = (float*)d_out;

    // workspace layout (as R19; feat is now the 4 quarter planes, same size):
    __half* Xh   = (__half*)d_ws;
    __half* feat = Xh + (size_t)N_NODES * KP1;
    __half* hbuf = feat + (size_t)N_NODES * HID;
    __half* Wp1  = hbuf + (size_t)N_NODES * HID;
    __half* Wp2  = Wp1 + 11 * 8 * 64 * 4;
    float*  el   = (float*)(Wp2 + 8 * 8 * 64 * 4);
    float*  er   = el + (size_t)N_NODES * HEADS;
    int* counts    = (int*)(er + (size_t)N_NODES * HEADS);
    int* rowptr    = counts + N_NODES;
    int* blockSums = rowptr + N_NODES + 1;
    int* csr_src   = blockSums + 256;
    int* rank      = (int*)hbuf;   // aliases hbuf (disjoint lifetimes)

    const int aggBlocks   = (N_NODES / 4) * 4;            // 50000 (quarter-split)
    const int headsBlocks = ((N_NODES + 255) / 256) * 2;  // 392 (node x MLP)
    const int edgeBlocks  = (N_EDGES + 255) / 256;        // 3907
    const int prepBlocks  = CVT_BLOCKS + PW1_BLOCKS + PW2_BLOCKS + NB_SCAN;
    const int sgBlocks    = SCAT_BLOCKS + GEMM_BLOCKS;    // 2830

    // 1. prep: cvt | pack_w1 | pack_w2 | zero_counts
    fused_prep<<<prepBlocks, 256, 0, stream>>>(features, Xh, W1, Wp1, W2, Wp2,
                                               counts);
    // 2. histogram + per-edge rank
    hist_dst_rank<<<edgeBlocks, 256, 0, stream>>>(dst, counts, rank);
    // 3-5. scan chain
    scan_local<<<NB_SCAN, 256, 0, stream>>>(counts, rowptr, blockSums);
    scan_sums<<<1, 256, 0, stream>>>(blockSums);
    add_offsets<<<NB_SCAN, 256, 0, stream>>>(rowptr, blockSums);
    // 6. atomic-free scatter || layer-1 GEMM
    fused_scatter_gemm1<<<sgBlocks, 256, 0, stream>>>(src, dst, rowptr, rank,
                                                      csr_src, Xh, Wp1,
                                                      al1, ar1, feat, el, er);
    // 7. layer-1 aggregation (quarter planes)
    gat_aggregate_quarter<<<aggBlocks, 256, 0, stream>>>(rowptr, csr_src,
                                                         el, er, feat, hbuf);
    // 8. layer-2 GEMM
    gemm_mfma2<<<GEMM_BLOCKS, 256, 0, stream>>>(hbuf, Wp2, al2, ar2,
                                                feat, el, er);
    // 9. layer-2 aggregation
    gat_aggregate_quarter<<<aggBlocks, 256, 0, stream>>>(rowptr, csr_src,
                                                         el, er, feat, hbuf);
    // 10. MLP heads
    heads_kernel<<<headsBlocks, 256, 0, stream>>>(hbuf, Wc1, bc1, Wc2, bc2,
                                                  Wf1, bf1, Wf2, bf2, out);
}

// Round 21
// 253.651 us; speedup vs baseline: 1.1646x; 1.1646x over previous
//
#include <hip/hip_runtime.h>
#include <hip/hip_fp16.h>
#include <math.h>

#define N_NODES 50000
#define N_EDGES 1000000
#define F_IN    165
#define KP1     176                         // F_IN padded to 16
#define HID     128
#define HEADS   4
#define F_OUT   32
#define NEG_SLOPE 0.2f
#define NB_SCAN  ((N_NODES + 255) / 256)   // 196 scan blocks
#define NPART    8                          // dst partitions (= XCDs)
#define PART_SZ  (N_NODES / NPART)          // 6250, exact
#define SCHUNKS  256                        // edge chunks for scatter
#define CVT_BLOCKS ((N_NODES * KP1 + 255) / 256)   // 34375
#define PW1_BLOCKS ((11 * 8 * 64 + 255) / 256)     // 22
#define PW2_BLOCKS ((8 * 8 * 64 + 255) / 256)      // 16
#define SCAT_BLOCKS (SCHUNKS * NPART)              // 2048
#define GEMM_BLOCKS ((N_NODES + 63) / 64)          // 782

typedef _Float16 half4v __attribute__((ext_vector_type(4)));
typedef float    f32x4  __attribute__((ext_vector_type(4)));

// ===== device bodies ==========================================================

__device__ __forceinline__ void cvt_body(int bid, const float* __restrict__ X,
                                         __half* __restrict__ Xh) {
    const long long i = (long long)bid * 256 + threadIdx.x;
    if (i >= (long long)N_NODES * KP1) return;
    const int n = (int)(i / KP1);
    const int k = (int)(i - (long long)n * KP1);
    Xh[i] = (k < F_IN) ? __float2half_rn(X[(long long)n * F_IN + k])
                       : __float2half_rn(0.f);
}

__device__ __forceinline__ void pack_body(int bid, const float* __restrict__ W,
                                          __half* __restrict__ Wp,
                                          int K, int ksteps) {
    const int idx = bid * 256 + threadIdx.x;   // (kt*8+ct)*64 + lane
    if (idx >= ksteps * 8 * 64) return;
    const int lane = idx & 63;
    const int tile = idx >> 6;
    const int ct = tile & 7;
    const int kt = tile >> 3;
    const int col = ct * 16 + (lane & 15);
    const int k0 = kt * 16 + 4 * (lane >> 4);
#pragma unroll
    for (int i = 0; i < 4; ++i) {
        const int k = k0 + i;
        Wp[(size_t)idx * 4 + i] = (k < K) ? __float2half_rn(W[(size_t)k * HID + col])
                                          : __float2half_rn(0.f);
    }
}

template <int KSTEPS, int KP>
__device__ __forceinline__ void gemm_body(int bid, const __half* __restrict__ Xh,
                                          const __half* __restrict__ Wp,
                                          const float* __restrict__ al,
                                          const float* __restrict__ ar,
                                          __half* __restrict__ feat,
                                          float* __restrict__ el,
                                          float* __restrict__ er) {
    const int tid  = threadIdx.x;
    const int wav  = tid >> 6;
    const int lane = tid & 63;
    const int base = bid * 64 + wav * 16;            // 16-row slice per wave
    if (base >= N_NODES) return;
    const int lr = lane & 15;                         // row (A) / col (B,D)
    const int lq = lane >> 4;                         // k-quad / row-quad

    f32x4 acc[8];
#pragma unroll
    for (int ct = 0; ct < 8; ++ct) acc[ct] = (f32x4){0.f, 0.f, 0.f, 0.f};

    const __half* arow = Xh + (size_t)(base + lr) * KP + 4 * lq;
    for (int kt = 0; kt < KSTEPS; ++kt) {
        const half4v a = *reinterpret_cast<const half4v*>(arow + kt * 16);
        const __half* bp = Wp + ((size_t)kt * 8 * 64 + lane) * 4;
#pragma unroll
        for (int ct = 0; ct < 8; ++ct) {
            const half4v b = *reinterpret_cast<const half4v*>(bp + (size_t)ct * 256);
            acc[ct] = __builtin_amdgcn_mfma_f32_16x16x16f16(a, b, acc[ct], 0, 0, 0);
        }
    }

    float alv[8], arv[8];
#pragma unroll
    for (int ct = 0; ct < 8; ++ct) {
        const int h = ct >> 1;
        const int f = (ct & 1) * 16 + lr;
        alv[ct] = al[h * F_OUT + f];
        arv[ct] = ar[h * F_OUT + f];
    }

#pragma unroll
    for (int i = 0; i < 4; ++i) {
        const int node = base + 4 * lq + i;           // D row = 4*lq + i
#pragma unroll
        for (int ct = 0; ct < 8; ++ct)
            feat[(size_t)node * HID + ct * 16 + lr] = __float2half_rn(acc[ct][i]);
#pragma unroll
        for (int h = 0; h < 4; ++h) {
            float pl = acc[2 * h][i] * alv[2 * h] + acc[2 * h + 1][i] * alv[2 * h + 1];
            float pr = acc[2 * h][i] * arv[2 * h] + acc[2 * h + 1][i] * arv[2 * h + 1];
            pl += __shfl_xor(pl, 1); pr += __shfl_xor(pr, 1);
            pl += __shfl_xor(pl, 2); pr += __shfl_xor(pr, 2);
            pl += __shfl_xor(pl, 4); pr += __shfl_xor(pr, 4);
            pl += __shfl_xor(pl, 8); pr += __shfl_xor(pr, 8);
            if (lr == 0) {
                el[node * HEADS + h] = pl;
                er[node * HEADS + h] = pr;
            }
        }
    }
}

// rank-based scatter: NO atomics. pos = rowptr[d] + rank[e] where rank was
// assigned by hist's atomicAdd return value. Partition filter keeps all
// writers of a csr_src line on one XCD (round-robin bid->XCD).
__device__ __forceinline__ void scatter_body(int bid, const int* __restrict__ src,
                                             const int* __restrict__ dst,
                                             const int* __restrict__ rowptr,
                                             const int* __restrict__ rank,
                                             int* __restrict__ csr_src) {
    const int part  = bid & (NPART - 1);
    const int chunk = bid >> 3;
    constexpr int CE = (N_EDGES + SCHUNKS - 1) / SCHUNKS;   // 3907
    const int e0 = chunk * CE;
    const int e1 = min(e0 + CE, N_EDGES);
    for (int e = e0 + threadIdx.x; e < e1; e += 256) {
        const int d = dst[e];
        if (d / PART_SZ == part)
            csr_src[rowptr[d] + rank[e]] = src[e];
    }
}

// ===== launch-graph compaction ================================================

// A: cvt_features | pack_w1 | pack_w2 | zero_counts (all mutually independent)
__global__ __launch_bounds__(256) void fused_prep(const float* __restrict__ X,
                                                  __half* __restrict__ Xh,
                                                  const float* __restrict__ W1,
                                                  __half* __restrict__ Wp1,
                                                  const float* __restrict__ W2,
                                                  __half* __restrict__ Wp2,
                                                  int* __restrict__ counts) {
    int bid = blockIdx.x;
    if (bid < CVT_BLOCKS) { cvt_body(bid, X, Xh); return; }
    bid -= CVT_BLOCKS;
    if (bid < PW1_BLOCKS) { pack_body(bid, W1, Wp1, F_IN, 11); return; }
    bid -= PW1_BLOCKS;
    if (bid < PW2_BLOCKS) { pack_body(bid, W2, Wp2, HID, 8); return; }
    bid -= PW2_BLOCKS;
    const int i = bid * 256 + threadIdx.x;
    if (i < N_NODES) counts[i] = 0;
}

// histogram + per-edge rank (the atomicAdd return value IS the rank)
__global__ __launch_bounds__(256) void hist_dst_rank(const int* __restrict__ dst,
                                                     int* __restrict__ counts,
                                                     int* __restrict__ rank) {
    const int e = blockIdx.x * 256 + threadIdx.x;
    if (e < N_EDGES) rank[e] = atomicAdd(&counts[dst[e]], 1);
}

// F: scatter (rank-based, atomic-free) | gemm1 (independent -> overlap)
__global__ __launch_bounds__(256) void fused_scatter_gemm1(
        const int* __restrict__ src, const int* __restrict__ dst,
        const int* __restrict__ rowptr, const int* __restrict__ rank,
        int* __restrict__ csr_src,
        const __half* __restrict__ Xh, const __half* __restrict__ Wp1,
        const float* __restrict__ al1, const float* __restrict__ ar1,
        __half* __restrict__ feat, float* __restrict__ el,
        float* __restrict__ er) {
    if (blockIdx.x < SCAT_BLOCKS)
        scatter_body(blockIdx.x, src, dst, rowptr, rank, csr_src);
    else
        gemm_body<11, KP1>(blockIdx.x - SCAT_BLOCKS, Xh, Wp1, al1, ar1,
                           feat, el, er);
}

// layer-2 GEMM standalone
__global__ __launch_bounds__(256) void gemm_mfma2(const __half* __restrict__ Xh,
                                                  const __half* __restrict__ Wp,
                                                  const float* __restrict__ al,
                                                  const float* __restrict__ ar,
                                                  __half* __restrict__ feat,
                                                  float* __restrict__ el,
                                                  float* __restrict__ er) {
    gemm_body<8, HID>(blockIdx.x, Xh, Wp, al, ar, feat, el, er);
}

// ================= scan chain =================================================

__global__ __launch_bounds__(256) void scan_local(const int* __restrict__ counts,
                                                  int* __restrict__ rowptr,
                                                  int* __restrict__ blockSums) {
    __shared__ int tmp[256];
    const int i = blockIdx.x * 256 + threadIdx.x;
    const int v = (i < N_NODES) ? counts[i] : 0;
    tmp[threadIdx.x] = v;
    __syncthreads();
#pragma unroll
    for (int off = 1; off < 256; off <<= 1) {
        int t = (threadIdx.x >= off) ? tmp[threadIdx.x - off] : 0;
        __syncthreads();
        tmp[threadIdx.x] += t;
        __syncthreads();
    }
    if (i < N_NODES) rowptr[i] = tmp[threadIdx.x] - v;
    if (threadIdx.x == 255) blockSums[blockIdx.x] = tmp[255];
}

__global__ __launch_bounds__(256) void scan_sums(int* __restrict__ blockSums) {
    __shared__ int tmp[256];
    const int v = (threadIdx.x < NB_SCAN) ? blockSums[threadIdx.x] : 0;
    tmp[threadIdx.x] = v;
    __syncthreads();
#pragma unroll
    for (int off = 1; off < 256; off <<= 1) {
        int t = (threadIdx.x >= off) ? tmp[threadIdx.x - off] : 0;
        __syncthreads();
        tmp[threadIdx.x] += t;
        __syncthreads();
    }
    if (threadIdx.x < NB_SCAN) blockSums[threadIdx.x] = tmp[threadIdx.x] - v;
}

__global__ __launch_bounds__(256) void add_offsets(int* __restrict__ rowptr,
                                                   const int* __restrict__ blockSums) {
    const int i = blockIdx.x * 256 + threadIdx.x;
    if (i < N_NODES)
        rowptr[i] = rowptr[i] + blockSums[blockIdx.x];
    if (i == 0) rowptr[N_NODES] = N_EDGES;
}

// ===== GAT aggregation: feature-half XCD affinity + edge-parity lanes ========
// (verbatim R17-R19, passed; measured optimum of the split family)
__global__ __launch_bounds__(256) void gat_aggregate_half(const int* __restrict__ rowptr,
                                                          const int* __restrict__ csr_src,
                                                          const float* __restrict__ el,
                                                          const float* __restrict__ er,
                                                          const __half* __restrict__ feat,
                                                          __half* __restrict__ outh) {
    const int bid  = blockIdx.x;
    const int half = bid & 1;
    const int d    = (bid >> 1) * 4 + (threadIdx.x >> 6);
    if (d >= N_NODES) return;
    const int lane = threadIdx.x & 63;
    const int ep   = lane >> 5;               // edge-parity group 0/1
    const int c    = lane & 31;               // __half2 index within half
    const int h    = (half << 1) | (c >> 4);  // head owning features 2c,2c+1
    const int start = rowptr[d], end = rowptr[d + 1];
    const float erd = er[d * HEADS + h];
    const __half2* __restrict__ feat2 = (const __half2*)feat;  // row stride 64
    const unsigned coff = (unsigned)(half * 32 + c);

    float denom = 0.f, ax = 0.f, ay = 0.f;
    for (int chunk = start; chunk < end; chunk += 64) {
        const int cnt = min(64, end - chunk);
        const int idx = chunk + lane;
        const int sv = csr_src[idx < end ? idx : start];
        int t = 0;
        for (; t + 8 <= cnt; t += 8) {   // group ep: edges t+ep, +2, +4, +6
            const unsigned s0 = (unsigned)__shfl(sv, t + ep);
            const unsigned s1 = (unsigned)__shfl(sv, t + 2 + ep);
            const unsigned s2 = (unsigned)__shfl(sv, t + 4 + ep);
            const unsigned s3 = (unsigned)__shfl(sv, t + 6 + ep);
            const float e0 = el[s0 * 4u + h];
            const float e1 = el[s1 * 4u + h];
            const float e2 = el[s2 * 4u + h];
            const float e3 = el[s3 * 4u + h];
            const __half2 q0 = feat2[s0 * 64u + coff];
            const __half2 q1 = feat2[s1 * 64u + coff];
            const __half2 q2 = feat2[s2 * 64u + coff];
            const __half2 q3 = feat2[s3 * 64u + coff];
            float v0 = e0 + erd; v0 = fmaxf(v0, NEG_SLOPE * v0);
            float v1 = e1 + erd; v1 = fmaxf(v1, NEG_SLOPE * v1);
            float v2 = e2 + erd; v2 = fmaxf(v2, NEG_SLOPE * v2);
            float v3 = e3 + erd; v3 = fmaxf(v3, NEG_SLOPE * v3);
            const float x0 = __expf(v0);
            const float x1 = __expf(v1);
            const float x2 = __expf(v2);
            const float x3 = __expf(v3);
            const float2 f0 = __half22float2(q0);
            const float2 f1 = __half22float2(q1);
            const float2 f2 = __half22float2(q2);
            const float2 f3 = __half22float2(q3);
            denom += (x0 + x1) + (x2 + x3);
            ax += f0.x * x0 + f1.x * x1 + f2.x * x2 + f3.x * x3;
            ay += f0.y * x0 + f1.y * x1 + f2.y * x2 + f3.y * x3;
        }
        for (; t < cnt; t += 2) {        // masked tail
            const int e = t + ep;
            const int ei = e < cnt ? e : 0;
            const unsigned s0 = (unsigned)__shfl(sv, ei);
            const float e0 = el[s0 * 4u + h];
            const __half2 q0 = feat2[s0 * 64u + coff];
            float v0 = e0 + erd; v0 = fmaxf(v0, NEG_SLOPE * v0);
            float x0 = __expf(v0);
            if (e >= cnt) x0 = 0.f;
            const float2 f0 = __half22float2(q0);
            denom += x0;
            ax += f0.x * x0;
            ay += f0.y * x0;
        }
    }

    // combine the two edge-parity groups (no LDS, no barrier)
    ax    += __shfl_xor(ax, 32);
    ay    += __shfl_xor(ay, 32);
    denom += __shfl_xor(denom, 32);

    const float inv = 1.f / fmaxf(denom, 1e-9f);
    if (ep == 0)
        ((__half2*)outh)[(size_t)d * 64 + coff] =
            __floats2half2_rn(fmaxf(ax * inv, 0.f), fmaxf(ay * inv, 0.f));
}

// ===== MLP heads: thread per (node, MLP) — zero shuffles (verbatim R17) ======
__global__ __launch_bounds__(256) void heads_kernel(const __half* __restrict__ hbuf,
                                                    const float* __restrict__ Wc1,
                                                    const float* __restrict__ bc1,
                                                    const float* __restrict__ Wc2,
                                                    const float* __restrict__ bc2,
                                                    const float* __restrict__ Wf1,
                                                    const float* __restrict__ bf1,
                                                    const float* __restrict__ Wf2,
                                                    const float* __restrict__ bf2,
                                                    float* __restrict__ out) {
    const int which = blockIdx.x & 1;                  // 0=class, 1=confidence
    const int n = (blockIdx.x >> 1) * 256 + threadIdx.x;
    if (n >= N_NODES) return;
    const float* __restrict__ W1 = which ? Wf1 : Wc1;
    const float* __restrict__ b1 = which ? bf1 : bc1;
    const float* __restrict__ W2 = which ? Wf2 : Wc2;
    const float* __restrict__ b2 = which ? bf2 : bc2;
    const __half2* __restrict__ hrow = (const __half2*)hbuf + (size_t)n * 64;

    float a[10];
#pragma unroll
    for (int o = 0; o < 10; ++o) a[o] = b1[o];
    for (int j = 0; j < 64; ++j) {
        const float2 x = __half22float2(hrow[j]);
#pragma unroll
        for (int o = 0; o < 10; ++o)
            a[o] += x.x * W1[(2 * j) * 10 + o] + x.y * W1[(2 * j + 1) * 10 + o];
    }
    float p = b2[0];
#pragma unroll
    for (int o = 0; o < 10; ++o) p += fmaxf(a[o], 0.f) * W2[o];
    out[which * N_NODES + n] = which ? 1.0f / (1.0f + __expf(-p)) : p;
}

extern "C" void kernel_launch(void* const* d_in, const int* in_sizes, int n_in,
                              void* d_out, int out_size, void* d_ws, size_t ws_size,
                              hipStream_t stream) {
    const float* features = (const float*)d_in[0];
    const int*   src      = (const int*)d_in[1];
    const int*   dst      = (const int*)d_in[2];
    const float* W1  = (const float*)d_in[3];
    const float* al1 = (const float*)d_in[4];
    const float* ar1 = (const float*)d_in[5];
    const float* W2  = (const float*)d_in[6];
    const float* al2 = (const float*)d_in[7];
    const float* ar2 = (const float*)d_in[8];
    const float* Wc1 = (const float*)d_in[9];
    const float* bc1 = (const float*)d_in[10];
    const float* Wc2 = (const float*)d_in[11];
    const float* bc2 = (const float*)d_in[12];
    const float* Wf1 = (const float*)d_in[13];
    const float* bf1 = (const float*)d_in[14];
    const float* Wf2 = (const float*)d_in[15];
    const float* bf2 = (const float*)d_in[16];
    float* out = (float*)d_out;

    // workspace layout:
    // Xh[N*176] | feat[N*128] | hbuf[N*128] | Wp1 | Wp2
    // | el[4N] f32 | er[4N] f32 | counts | rowptr | blockSums | csr_src
    // rank[E] (4MB) ALIASES hbuf: rank lives [hist..scatter], hbuf lives
    // [agg1..heads] — disjoint.
    __half* Xh   = (__half*)d_ws;
    __half* feat = Xh + (size_t)N_NODES * KP1;
    __half* hbuf = feat + (size_t)N_NODES * HID;
    __half* Wp1  = hbuf + (size_t)N_NODES * HID;
    __half* Wp2  = Wp1 + 11 * 8 * 64 * 4;
    float*  el   = (float*)(Wp2 + 8 * 8 * 64 * 4);
    float*  er   = el + (size_t)N_NODES * HEADS;
    int* counts    = (int*)(er + (size_t)N_NODES * HEADS);
    int* rowptr    = counts + N_NODES;
    int* blockSums = rowptr + N_NODES + 1;
    int* csr_src   = blockSums + 256;
    int* rank      = (int*)hbuf;

    const int aggBlocks   = (N_NODES / 4) * 2;            // 25000 (half-split)
    const int headsBlocks = ((N_NODES + 255) / 256) * 2;  // 392 (node x MLP)
    const int edgeBlocks  = (N_EDGES + 255) / 256;        // 3907
    const int prepBlocks  = CVT_BLOCKS + PW1_BLOCKS + PW2_BLOCKS + NB_SCAN;
    const int sgBlocks    = SCAT_BLOCKS + GEMM_BLOCKS;    // 2830

    // 1. prep: cvt | pack_w1 | pack_w2 | zero_counts (independent sections)
    fused_prep<<<prepBlocks, 256, 0, stream>>>(features, Xh, W1, Wp1, W2, Wp2,
                                               counts);
    // 2. histogram + per-edge rank (atomicAdd return value)
    hist_dst_rank<<<edgeBlocks, 256, 0, stream>>>(dst, counts, rank);
    // 3-5. scan chain
    scan_local<<<NB_SCAN, 256, 0, stream>>>(counts, rowptr, blockSums);
    scan_sums<<<1, 256, 0, stream>>>(blockSums);
    add_offsets<<<NB_SCAN, 256, 0, stream>>>(rowptr, blockSums);
    // 6. atomic-free scatter || layer-1 GEMM (independent; overlap)
    fused_scatter_gemm1<<<sgBlocks, 256, 0, stream>>>(src, dst, rowptr, rank,
                                                      csr_src, Xh, Wp1,
                                                      al1, ar1, feat, el, er);
    // 7. layer-1 aggregation
    gat_aggregate_half<<<aggBlocks, 256, 0, stream>>>(rowptr, csr_src, el, er,
                                                      feat, hbuf);
    // 8. layer-2 GEMM
    gemm_mfma2<<<GEMM_BLOCKS, 256, 0, stream>>>(hbuf, Wp2, al2, ar2,
                                                feat, el, er);
    // 9. layer-2 aggregation
    gat_aggregate_half<<<aggBlocks, 256, 0, stream>>>(rowptr, csr_src, el, er,
                                                      feat, hbuf);
    // 10. MLP heads
    heads_kernel<<<headsBlocks, 256, 0, stream>>>(hbuf, Wc1, bc1, Wc2, bc2,
                                                  Wf1, bf1, Wf2, bf2, out);
}